// Round 8
// baseline (467.926 us; speedup 1.0000x reference)
//
#include <hip/hip_runtime.h>

#define T_TOK 8192
#define H_DIM 4096
#define O_DIM 4096
#define R_RANK 16
#define N_AD 8

#define TB_S 32      // tokens per tile (shrink & expand)
#define HSPLIT 4     // h-range splits (grid.y of shrink)
#define HRANGE (H_DIM / HSPLIT)   // 1024 h per block
#define CHUNK 128    // h per chunk iteration (8 chunks, register-resident)
#define OB 1024      // output columns per expand block
#define NTILE_MAX (T_TOK / TB_S + N_AD)   // 264: worst-case tile count

// ---------------- sort: bucket tokens by adapter (ballot-based) ----------------
__global__ void hist_kernel(const int* __restrict__ idx, int* __restrict__ cnt) {
    const int t = blockIdx.x * 256 + threadIdx.x;   // grid 32x256 = 8192 exactly
    const int a = idx[t];
    const int lane = threadIdx.x & 63;
    #pragma unroll
    for (int k = 0; k < N_AD; ++k) {
        unsigned long long m = __ballot(a == k);
        if (lane == 0 && m) atomicAdd(&cnt[k], (int)__popcll(m));
    }
}

__global__ void scan_kernel(const int* __restrict__ cnt, int* __restrict__ base,
                            int* __restrict__ cur, int* __restrict__ tbase) {
    int s = 0, tt = 0;
    #pragma unroll
    for (int a = 0; a < N_AD; ++a) {
        base[a] = s; cur[a] = s; tbase[a] = tt;
        s += cnt[a]; tt += (cnt[a] + TB_S - 1) / TB_S;
    }
    base[N_AD] = s; tbase[N_AD] = tt;
}

__global__ void scatter_kernel(const int* __restrict__ idx, int* __restrict__ cur,
                               int* __restrict__ list) {
    const int t = blockIdx.x * 256 + threadIdx.x;
    const int a = idx[t];
    const int lane = threadIdx.x & 63;
    const unsigned long long lt_mask = (1ull << lane) - 1ull;
    #pragma unroll
    for (int k = 0; k < N_AD; ++k) {
        unsigned long long m = __ballot(a == k);
        if (m) {
            int s = 0;
            if (lane == 0) s = atomicAdd(&cur[k], (int)__popcll(m));
            s = __shfl(s, 0);
            if (a == k) list[s + (int)__popcll(m & lt_mask)] = t;
        }
    }
}

// tile search: a = largest k with tbase[k] <= b  (requires b < tbase[N_AD])
__device__ __forceinline__ int find_adapter(const int* stb, int b) {
    int a = 0;
    #pragma unroll
    for (int k = 1; k < N_AD; ++k) if (b >= stb[k]) a = k;
    return a;
}

// ---------------- shrink v3: barrier-free main loop, A direct from L2 ----------------
// grid: (NTILE_MAX, HSPLIT), 256 threads.
// thread: tg = tid&7 -> 4-token group; hs = tid>>3 (0..31) -> 4 consecutive h rows
// per 128-h chunk. x and A both read straight from global into registers; the 8
// lanes sharing an A row issue identical addresses (merged by the coalescer).
__global__ __launch_bounds__(256, 4) void shrink_kernel(
    const float* __restrict__ x, const float* __restrict__ lora_a,
    const int* __restrict__ list, const int* __restrict__ base,
    const int* __restrict__ tbase, float* __restrict__ V4) {
    __shared__ int stb[N_AD + 1];
    __shared__ int toks[TB_S];
    __shared__ float red2[4][8][4][16];     // 8 KB cross-wave reduction

    const int tid = threadIdx.x;
    if (tid <= N_AD) stb[tid] = tbase[tid];
    __syncthreads();

    const int b = blockIdx.x;
    if (b >= stb[N_AD]) return;
    const int a = find_adapter(stb, b);
    const int s0 = base[a], s1 = base[a + 1];
    const int start = s0 + (b - stb[a]) * TB_S;
    const int nt = min(TB_S, s1 - start);

    if (tid < TB_S) toks[tid] = (tid < nt) ? list[start + tid] : -1;
    __syncthreads();

    const int hs = tid >> 3;                 // 0..31
    const int tg = tid & 7;
    const int h0 = blockIdx.y * HRANGE + (hs << 2);   // thread's first h row

    // hoist token row pointers + validity masks into registers
    const float* xp[4];
    float msk[4];
    #pragma unroll
    for (int i = 0; i < 4; ++i) {
        const int t = toks[(tg << 2) + i];
        msk[i] = (t >= 0) ? 1.f : 0.f;
        xp[i] = x + (size_t)(t >= 0 ? t : 0) * H_DIM + h0;
    }
    const float* ap = lora_a + (size_t)a * H_DIM * R_RANK + (size_t)h0 * R_RANK;

    float acc[4][16];
    #pragma unroll
    for (int i = 0; i < 4; ++i)
        #pragma unroll
        for (int r = 0; r < 16; ++r) acc[i][r] = 0.f;

    // 8 chunks of 128 h; NO barriers — waves free-run, loads pipeline across chunks
    #pragma unroll 2
    for (int c = 0; c < HRANGE / CHUNK; ++c) {
        const int xoff = c * CHUNK;                 // floats
        const size_t aoff = (size_t)c * CHUNK * R_RANK;
        float4 xv[4];
        #pragma unroll
        for (int i = 0; i < 4; ++i) {
            xv[i] = *(const float4*)(xp[i] + xoff);
            xv[i].x *= msk[i]; xv[i].y *= msk[i];
            xv[i].z *= msk[i]; xv[i].w *= msk[i];
        }
        #pragma unroll
        for (int j = 0; j < 4; ++j) {               // 4 consecutive A rows
            const float* ar = ap + aoff + (size_t)j * R_RANK;
            const float4 a0 = *(const float4*)(ar + 0);
            const float4 a1 = *(const float4*)(ar + 4);
            const float4 a2 = *(const float4*)(ar + 8);
            const float4 a3 = *(const float4*)(ar + 12);
            #pragma unroll
            for (int i = 0; i < 4; ++i) {
                const float xs = (j == 0) ? xv[i].x : (j == 1) ? xv[i].y
                               : (j == 2) ? xv[i].z : xv[i].w;
                acc[i][0]  += xs * a0.x; acc[i][1]  += xs * a0.y;
                acc[i][2]  += xs * a0.z; acc[i][3]  += xs * a0.w;
                acc[i][4]  += xs * a1.x; acc[i][5]  += xs * a1.y;
                acc[i][6]  += xs * a1.z; acc[i][7]  += xs * a1.w;
                acc[i][8]  += xs * a2.x; acc[i][9]  += xs * a2.y;
                acc[i][10] += xs * a2.z; acc[i][11] += xs * a2.w;
                acc[i][12] += xs * a3.x; acc[i][13] += xs * a3.y;
                acc[i][14] += xs * a3.z; acc[i][15] += xs * a3.w;
            }
        }
    }

    // reduce over 32 h-strips: shuffle over in-wave hs (lane bits 3..5), then LDS over 4 waves
    #pragma unroll
    for (int i = 0; i < 4; ++i)
        #pragma unroll
        for (int r = 0; r < 16; ++r) {
            float f = acc[i][r];
            f += __shfl_xor(f, 8);
            f += __shfl_xor(f, 16);
            f += __shfl_xor(f, 32);
            acc[i][r] = f;
        }
    const int lane = tid & 63, w = tid >> 6;
    if ((lane >> 3) == 0) {
        #pragma unroll
        for (int i = 0; i < 4; ++i)
            #pragma unroll
            for (int q = 0; q < 4; ++q)
                *(float4*)&red2[w][tg][i][q << 2] =
                    make_float4(acc[i][(q << 2)], acc[i][(q << 2) + 1],
                                acc[i][(q << 2) + 2], acc[i][(q << 2) + 3]);
    }
    __syncthreads();
    if (tid < 128) {
        const int tl = tid >> 2, q = tid & 3;
        const int tg2 = tl >> 2, i2 = tl & 3;
        float4 s = make_float4(0.f, 0.f, 0.f, 0.f);
        #pragma unroll
        for (int w2 = 0; w2 < 4; ++w2) {
            const float4 p = *(const float4*)&red2[w2][tg2][i2][q << 2];
            s.x += p.x; s.y += p.y; s.z += p.z; s.w += p.w;
        }
        const int t = toks[tl];
        if (t >= 0)
            *(float4*)&V4[((size_t)blockIdx.y * T_TOK + t) * R_RANK + (q << 2)] = s;
    }
}

// ---------------- expand: out[t] = result[t] + (sum_split V4) @ B[a] ----------------
// grid: (NTILE_MAX, O/OB), 256 threads; thread owns 1 float4 of o, B[16] in regs.
// unroll 4 tokens -> 4 result-loads in flight per thread.
__global__ __launch_bounds__(256, 4) void expand_kernel(
    const float* __restrict__ result, const float* __restrict__ lora_b,
    const float* __restrict__ V4, const int* __restrict__ list,
    const int* __restrict__ base, const int* __restrict__ tbase,
    float* __restrict__ out) {
    __shared__ int stb[N_AD + 1];
    __shared__ float v_lds[TB_S][16];
    __shared__ int toks[TB_S];

    const int tid = threadIdx.x;
    if (tid <= N_AD) stb[tid] = tbase[tid];
    __syncthreads();

    const int b = blockIdx.x;
    if (b >= stb[N_AD]) return;
    const int a = find_adapter(stb, b);
    const int s0 = base[a], s1 = base[a + 1];
    const int start = s0 + (b - stb[a]) * TB_S;
    const int nt = min(TB_S, s1 - start);

    if (tid < TB_S) toks[tid] = (tid < nt) ? list[start + tid] : -1;
    __syncthreads();
    if (tid < 128) {
        const int tl = tid >> 2, q = tid & 3;
        const int t = toks[tl];
        float4 s = make_float4(0.f, 0.f, 0.f, 0.f);
        if (t >= 0) {
            #pragma unroll
            for (int sp = 0; sp < HSPLIT; ++sp) {
                const float4 p = *(const float4*)
                    &V4[((size_t)sp * T_TOK + t) * R_RANK + (q << 2)];
                s.x += p.x; s.y += p.y; s.z += p.z; s.w += p.w;
            }
        }
        *(float4*)&v_lds[tl][q << 2] = s;
    }

    const size_t o0 = (size_t)blockIdx.y * OB + ((size_t)tid << 2);
    const float* Bb = lora_b + (size_t)a * R_RANK * O_DIM + o0;
    float4 bb[16];
    #pragma unroll
    for (int r = 0; r < 16; ++r) bb[r] = *(const float4*)&Bb[(size_t)r * O_DIM];
    __syncthreads();

    int tl = 0;
    for (; tl + 4 <= nt; tl += 4) {
        const int t0 = toks[tl], t1 = toks[tl + 1], t2 = toks[tl + 2], t3 = toks[tl + 3];
        float4 acc0 = *(const float4*)&result[(size_t)t0 * O_DIM + o0];
        float4 acc1 = *(const float4*)&result[(size_t)t1 * O_DIM + o0];
        float4 acc2 = *(const float4*)&result[(size_t)t2 * O_DIM + o0];
        float4 acc3 = *(const float4*)&result[(size_t)t3 * O_DIM + o0];
        #pragma unroll
        for (int r = 0; r < 16; ++r) {
            const float v0 = v_lds[tl][r], v1 = v_lds[tl + 1][r];
            const float v2 = v_lds[tl + 2][r], v3 = v_lds[tl + 3][r];
            acc0.x += v0 * bb[r].x; acc0.y += v0 * bb[r].y;
            acc0.z += v0 * bb[r].z; acc0.w += v0 * bb[r].w;
            acc1.x += v1 * bb[r].x; acc1.y += v1 * bb[r].y;
            acc1.z += v1 * bb[r].z; acc1.w += v1 * bb[r].w;
            acc2.x += v2 * bb[r].x; acc2.y += v2 * bb[r].y;
            acc2.z += v2 * bb[r].z; acc2.w += v2 * bb[r].w;
            acc3.x += v3 * bb[r].x; acc3.y += v3 * bb[r].y;
            acc3.z += v3 * bb[r].z; acc3.w += v3 * bb[r].w;
        }
        *(float4*)&out[(size_t)t0 * O_DIM + o0] = acc0;
        *(float4*)&out[(size_t)t1 * O_DIM + o0] = acc1;
        *(float4*)&out[(size_t)t2 * O_DIM + o0] = acc2;
        *(float4*)&out[(size_t)t3 * O_DIM + o0] = acc3;
    }
    for (; tl < nt; ++tl) {
        const int t0 = toks[tl];
        float4 acc0 = *(const float4*)&result[(size_t)t0 * O_DIM + o0];
        #pragma unroll
        for (int r = 0; r < 16; ++r) {
            const float v0 = v_lds[tl][r];
            acc0.x += v0 * bb[r].x; acc0.y += v0 * bb[r].y;
            acc0.z += v0 * bb[r].z; acc0.w += v0 * bb[r].w;
        }
        *(float4*)&out[(size_t)t0 * O_DIM + o0] = acc0;
    }
}

extern "C" void kernel_launch(void* const* d_in, const int* in_sizes, int n_in,
                              void* d_out, int out_size, void* d_ws, size_t ws_size,
                              hipStream_t stream) {
    const float* result = (const float*)d_in[0];
    const float* x      = (const float*)d_in[1];
    const float* lora_a = (const float*)d_in[2];
    const float* lora_b = (const float*)d_in[3];
    const int*   aidx   = (const int*)d_in[4];
    float* out = (float*)d_out;

    char* ws = (char*)d_ws;
    float* V4   = (float*)ws;                                    // 4*T*16*4 = 2 MB
    size_t off  = (size_t)HSPLIT * T_TOK * R_RANK * 4;
    int* list   = (int*)(ws + off);   off += (size_t)T_TOK * 4;  // 32 KB
    int* base   = (int*)(ws + off);   off += 16 * 4;
    int* cnt    = (int*)(ws + off);   off += 16 * 4;
    int* cur    = (int*)(ws + off);   off += 16 * 4;
    int* tbase  = (int*)(ws + off);

    hipMemsetAsync(cnt, 0, N_AD * sizeof(int), stream);
    hist_kernel<<<T_TOK / 256, 256, 0, stream>>>(aidx, cnt);
    scan_kernel<<<1, 1, 0, stream>>>(cnt, base, cur, tbase);
    scatter_kernel<<<T_TOK / 256, 256, 0, stream>>>(aidx, cur, list);
    shrink_kernel<<<dim3(NTILE_MAX, HSPLIT), 256, 0, stream>>>(
        x, lora_a, list, base, tbase, V4);
    expand_kernel<<<dim3(NTILE_MAX, O_DIM / OB), 256, 0, stream>>>(
        result, lora_b, V4, list, base, tbase, out);
}